// Round 3
// baseline (272.594 us; speedup 1.0000x reference)
//
#include <hip/hip_runtime.h>
#include <math.h>

#define BB  256
#define TCC 256
#define DD  2048

typedef float4 f4;
typedef float __attribute__((ext_vector_type(4))) fv4;   // clang vector: ok for nontemporal builtins

// ---------------------------------------------------------------------------
// Kernel A: hw = h_dec @ W  (f32), split-K into 4 partials stored in d_ws.
// grid (32 e-tiles, 4 b-tiles, 4 k-splits), 256 threads.  (unchanged)
// ---------------------------------------------------------------------------
__global__ __launch_bounds__(256) void hw_gemm_partial(
    const float* __restrict__ h,     // [B][D]
    const float* __restrict__ W,     // [D][D]
    float* __restrict__ part)        // [4][B][D]
{
    __shared__ float hs[32][68];     // [d][b] transposed
    __shared__ float wsm[32][64];    // [d][e]

    const int tid = threadIdx.x;
    const int e0 = blockIdx.x * 64;
    const int b0 = blockIdx.y * 64;
    const int z  = blockIdx.z;

    float acc[4][4];
    #pragma unroll
    for (int i = 0; i < 4; i++)
        #pragma unroll
        for (int j = 0; j < 4; j++) acc[i][j] = 0.f;

    const int ie = tid & 15;
    const int ib = tid >> 4;

    const int hr = tid >> 2;
    const int hc = (tid & 3) * 8;
    const int wr = tid >> 3;
    const int wc = (tid & 7) * 8;

    for (int d0 = z * 512; d0 < z * 512 + 512; d0 += 32) {
        f4 ha = *(const f4*)&h[(size_t)(b0 + hr) * DD + d0 + hc];
        f4 hb = *(const f4*)&h[(size_t)(b0 + hr) * DD + d0 + hc + 4];
        hs[hc + 0][hr] = ha.x; hs[hc + 1][hr] = ha.y;
        hs[hc + 2][hr] = ha.z; hs[hc + 3][hr] = ha.w;
        hs[hc + 4][hr] = hb.x; hs[hc + 5][hr] = hb.y;
        hs[hc + 6][hr] = hb.z; hs[hc + 7][hr] = hb.w;
        f4 wa = *(const f4*)&W[(size_t)(d0 + wr) * DD + e0 + wc];
        f4 wb = *(const f4*)&W[(size_t)(d0 + wr) * DD + e0 + wc + 4];
        *(f4*)&wsm[wr][wc]     = wa;
        *(f4*)&wsm[wr][wc + 4] = wb;
        __syncthreads();

        #pragma unroll
        for (int dd = 0; dd < 32; dd++) {
            f4 hv = *(const f4*)&hs[dd][ib * 4];
            f4 wv = *(const f4*)&wsm[dd][ie * 4];
            float hvv[4] = {hv.x, hv.y, hv.z, hv.w};
            float wvv[4] = {wv.x, wv.y, wv.z, wv.w};
            #pragma unroll
            for (int i = 0; i < 4; i++)
                #pragma unroll
                for (int j = 0; j < 4; j++)
                    acc[i][j] += hvv[i] * wvv[j];
        }
        __syncthreads();
    }

    #pragma unroll
    for (int i = 0; i < 4; i++) {
        f4 v = make_float4(acc[i][0], acc[i][1], acc[i][2], acc[i][3]);
        *(f4*)&part[((size_t)z * BB + b0 + ib * 4 + i) * DD + e0 + ie * 4] = v;
    }
}

// ---------------------------------------------------------------------------
// Kernel B v2: wave-autonomous fused attention + concat copy.
// One block per b, 16 waves; wave w owns timesteps [16w, 16w+16).
// Lane ld owns float4 chunks at float offsets 4*ld + 256*j (j=0..7):
// every load/store instruction is a fully-coalesced 1KB wave access.
// No block barriers in the main loop; per-wave online softmax; single
// flash-style merge of the 16 wave-states at the end.
// ---------------------------------------------------------------------------
__global__ __launch_bounds__(1024) void attn_fused2(
    const float* __restrict__ h_dec,   // [B][D]
    const float* __restrict__ prev,    // [B][TC][D]
    const unsigned char* __restrict__ maskb,
    const float* __restrict__ part,    // [4][B][D] hw partials
    float* __restrict__ out)           // [B*D ctx | B*(TC+1)*D new_prev]
{
    __shared__ float hw[DD];
    __shared__ float ctx[DD];
    __shared__ float gm[16], gl[16];

    const int b   = blockIdx.x;
    const int tid = threadIdx.x;

    // reduce the 4 split-K partials -> hw row; zero ctx accumulator
    for (int k = tid; k < DD; k += 1024) {
        hw[k] = part[(size_t)b * DD + k]
              + part[((size_t)BB + b) * DD + k]
              + part[((size_t)2 * BB + b) * DD + k]
              + part[((size_t)3 * BB + b) * DD + k];
        ctx[k] = 0.f;
    }

    // mask dtype-layout detection: bool bytes -> nonzero bytes at k%4!=0
    int nz = 0;
    #pragma unroll
    for (int k = 1; k < 64; k++)
        if ((k & 3) != 0) nz += (maskb[k] != 0);
    const bool boolLayout = (nz > 0);
    const int* maski = (const int*)maskb;

    __syncthreads();

    const int w  = tid >> 6;     // wave 0..15
    const int ld = tid & 63;     // lane

    const float* pb = prev + (size_t)b * TCC * DD + 4 * ld;
    float* cp = out + (size_t)BB * DD + (size_t)b * (TCC + 1) * DD + 4 * ld;

    fv4 acc[8];
    #pragma unroll
    for (int j = 0; j < 8; j++) acc[j] = (fv4)(0.f);
    float m = -INFINITY, l = 0.f;

    for (int k = 0; k < 16; ++k) {
        const int t = w * 16 + k;
        const fv4* src = (const fv4*)(pb + (size_t)t * DD);
        fv4 v[8];
        #pragma unroll
        for (int j = 0; j < 8; ++j) v[j] = __builtin_nontemporal_load(src + 64 * j);

        fv4* dst = (fv4*)(cp + (size_t)t * DD);
        #pragma unroll
        for (int j = 0; j < 8; ++j) __builtin_nontemporal_store(v[j], dst + 64 * j);

        float p = 0.f;
        #pragma unroll
        for (int j = 0; j < 8; ++j) {
            const fv4 hv = *(const fv4*)&hw[4 * ld + 256 * j];
            p += v[j].x * hv.x + v[j].y * hv.y + v[j].z * hv.z + v[j].w * hv.w;
        }
        #pragma unroll
        for (int off = 32; off; off >>= 1) p += __shfl_xor(p, off, 64);

        const bool mk = boolLayout ? (maskb[(size_t)b * TCC + t] != 0)
                                   : (maski[(size_t)b * TCC + t] != 0);
        if (mk) {
            if (p > m) {
                const float s = __expf(m - p);   // m=-inf first time -> 0
                l *= s;
                #pragma unroll
                for (int j = 0; j < 8; j++) acc[j] *= s;
                m = p;
            }
            const float wgt = __expf(p - m);
            l += wgt;
            #pragma unroll
            for (int j = 0; j < 8; j++) acc[j] += wgt * v[j];
        }
    }

    if (ld == 0) { gm[w] = m; gl[w] = l; }
    __syncthreads();

    float mstar = -INFINITY;
    #pragma unroll
    for (int q = 0; q < 16; q++) mstar = fmaxf(mstar, gm[q]);
    float L = 0.f;
    #pragma unroll
    for (int q = 0; q < 16; q++) L += gl[q] * __expf(gm[q] - mstar);
    const float f = __expf(m - mstar);

    for (int ph = 0; ph < 16; ++ph) {
        if (w == ph) {
            #pragma unroll
            for (int j = 0; j < 8; ++j) {
                fv4* c = (fv4*)&ctx[4 * ld + 256 * j];
                *c += f * acc[j];
            }
        }
        __syncthreads();
    }

    const float invL = 1.0f / L;
    for (int k = tid; k < DD; k += 1024)
        out[(size_t)b * DD + k] = ctx[k] * invL;
    // append h_dec as row TC of new_prev
    for (int k = tid; k < DD; k += 1024)
        out[(size_t)BB * DD + ((size_t)b * (TCC + 1) + TCC) * DD + k] =
            h_dec[(size_t)b * DD + k];
}

extern "C" void kernel_launch(void* const* d_in, const int* in_sizes, int n_in,
                              void* d_out, int out_size, void* d_ws, size_t ws_size,
                              hipStream_t stream) {
    const float* h_dec = (const float*)d_in[0];
    const float* prev  = (const float*)d_in[1];
    const unsigned char* maskb = (const unsigned char*)d_in[2];
    const float* W = (const float*)d_in[3];
    float* out  = (float*)d_out;
    float* part = (float*)d_ws;   // 4 * B * D * 4 = 8 MB of scratch

    hipLaunchKernelGGL(hw_gemm_partial, dim3(32, 4, 4), dim3(256), 0, stream,
                       h_dec, W, part);
    hipLaunchKernelGGL(attn_fused2, dim3(BB), dim3(1024), 0, stream,
                       h_dec, prev, maskb, part, out);
}